// Round 10
// baseline (157.041 us; speedup 1.0000x reference)
//
#include <hip/hip_runtime.h>

typedef float f32x4 __attribute__((ext_vector_type(4)));
typedef short short8 __attribute__((ext_vector_type(8)));
typedef unsigned int u32;
typedef unsigned short u16;

#define CLL 0.25f                     // landmark self/neighbor coeff (deg=4)
#define CML 0.06019292654288460f      // 0.5/sqrt(69)
#define SELFM 0.014492753623188406f   // 1/69

__device__ __forceinline__ u16 f2bf(float x) {
  u32 b = __float_as_uint(x);
  return (u16)((b + 0x7FFFu + ((b >> 16) & 1u)) >> 16);
}
__device__ __forceinline__ u32 cvtpk(float a, float b) {
  u32 r;
  asm("v_cvt_pk_bf16_f32 %0, %1, %2" : "=v"(r) : "v"(a), "v"(b));
  return r;
}

// prep: (a) swizzle 7 HIDxHID weight mats into bf16 MFMA B-fragments;
//       (b) fold BN into per-layer affine sc/sh.  (unchanged from R6)
__global__ void prep(const float* __restrict__ midW, const float* __restrict__ lastW,
                     const float* __restrict__ bng, const float* __restrict__ bnb,
                     const float* __restrict__ bnm, const float* __restrict__ bnv,
                     u16* __restrict__ frag, float* __restrict__ bns) {
  const int t0 = blockIdx.x * blockDim.x + threadIdx.x;
  for (int u = t0; u < 7 * 4 * 2 * 64; u += gridDim.x * blockDim.x) {
    const int lane = u & 63;
    const int t = u >> 6;
    const int ks = t & 1;
    const int nt = (t >> 1) & 3;
    const int l = t >> 3;  // 0..6 -> layers 1..7
    const float* W = (l < 6) ? (midW + l * 4096) : lastW;
    const int col = nt * 16 + (lane & 15);
    const int kb = ks * 32 + (lane >> 4) * 8;
    u16* dst = frag + (size_t)u * 8;
#pragma unroll
    for (int j = 0; j < 8; ++j) dst[j] = f2bf(W[(kb + j) * 64 + col]);
  }
  for (int u = t0; u < 7 * 64; u += gridDim.x * blockDim.x) {
    const int l = u >> 6, f = u & 63;
    const float sc = (float)((double)bng[l * 64 + f] / sqrt((double)bnv[l * 64 + f] + 1e-5));
    bns[l * 128 + f] = sc;
    bns[l * 128 + 64 + f] = bnb[l * 64 + f] - bnm[l * 64 + f] * sc;
  }
}

#define SUM4(V) ((V)[0] + (V)[1] + (V)[2] + (V)[3])
#define MAX4(V) fmaxf(fmaxf((V)[0], (V)[1]), fmaxf((V)[2], (V)[3]))

// ring stencil for one 4-node run, BOTH col-sets; boundary values packed bf16.
#define STEP2(MT, TA, TPA, TNA, TB, TPB, TNB, HA, HB, RESID)           \
  {                                                                    \
    const float spA_ = (qg == 3) ? TPA[3] : TA[3];                     \
    const float spB_ = (qg == 3) ? TPB[3] : TB[3];                     \
    const u32 pvP_ = (u32)__shfl((int)cvtpk(spA_, spB_), (lane + 48) & 63, 64); \
    const float snA_ = (qg == 0) ? TNA[0] : TA[0];                     \
    const float snB_ = (qg == 0) ? TNB[0] : TB[0];                     \
    const u32 nvP_ = (u32)__shfl((int)cvtpk(snA_, snB_), (lane + 16) & 63, 64); \
    const float pvA_ = __uint_as_float(pvP_ << 16);                    \
    const float pvB_ = __uint_as_float(pvP_ & 0xffff0000u);            \
    const float nvA_ = __uint_as_float(nvP_ << 16);                    \
    const float nvB_ = __uint_as_float(nvP_ & 0xffff0000u);            \
    const float ta0A_ = ((MT) == 0 && qg == 0) ? tA4[3] : pvA_;        \
    const float ta0B_ = ((MT) == 0 && qg == 0) ? tB4[3] : pvB_;        \
    const float tb3A_ = ((MT) == 4 && qg == 0) ? tA0[0] : nvA_;        \
    const float tb3B_ = ((MT) == 4 && qg == 0) ? tB0[0] : nvB_;        \
    float oA0 = fmaf(CLL, ta0A_ + TA[0] + TA[1], cmtA_);               \
    float oA1 = fmaf(CLL, TA[0] + TA[1] + TA[2], cmtA_);               \
    float oA2 = fmaf(CLL, TA[1] + TA[2] + TA[3], cmtA_);               \
    float oA3 = fmaf(CLL, TA[2] + TA[3] + tb3A_, cmtA_);               \
    float oB0 = fmaf(CLL, ta0B_ + TB[0] + TB[1], cmtB_);               \
    float oB1 = fmaf(CLL, TB[0] + TB[1] + TB[2], cmtB_);               \
    float oB2 = fmaf(CLL, TB[1] + TB[2] + TB[3], cmtB_);               \
    float oB3 = fmaf(CLL, TB[2] + TB[3] + tb3B_, cmtB_);               \
    oA0 = fmaf(fmaxf(oA0, 0.f), scA_, shA_);                           \
    oA1 = fmaf(fmaxf(oA1, 0.f), scA_, shA_);                           \
    oA2 = fmaf(fmaxf(oA2, 0.f), scA_, shA_);                           \
    oA3 = fmaf(fmaxf(oA3, 0.f), scA_, shA_);                           \
    oB0 = fmaf(fmaxf(oB0, 0.f), scB_, shB_);                           \
    oB1 = fmaf(fmaxf(oB1, 0.f), scB_, shB_);                           \
    oB2 = fmaf(fmaxf(oB2, 0.f), scB_, shB_);                           \
    oB3 = fmaf(fmaxf(oB3, 0.f), scB_, shB_);                           \
    if (RESID) {                                                       \
      oA0 += HA[0]; oA1 += HA[1]; oA2 += HA[2]; oA3 += HA[3];          \
      oB0 += HB[0]; oB1 += HB[1]; oB2 += HB[2]; oB3 += HB[3];          \
    }                                                                  \
    HA[0] = oA0; HA[1] = oA1; HA[2] = oA2; HA[3] = oA3;                \
    HB[0] = oB0; HB[1] = oB1; HB[2] = oB2; HB[3] = oB3;                \
  }

// bf16 h write into swizzled hb for one col (4 scattered b16 stores)
#define WPAIR2(HW, MT, H, CQ)                                          \
  {                                                                    \
    const u32 pa = cvtpk(H[0], H[1]);                                  \
    const u32 pb = cvtpk(H[2], H[3]);                                  \
    (HW)[(16 * (MT) + 4 * qg + 0) * 64 + (CQ)] = (u16)pa;              \
    (HW)[(16 * (MT) + 4 * qg + 1) * 64 + ((CQ) ^ 8)] = (u16)(pa >> 16);\
    (HW)[(16 * (MT) + 4 * qg + 2) * 64 + ((CQ) ^ 16)] = (u16)pb;       \
    (HW)[(16 * (MT) + 4 * qg + 3) * 64 + ((CQ) ^ 24)] = (u16)(pb >> 16); \
  }

// full epilogue for both col-sets
#define EPILOG2(RESID, WRITE, HBW, BA, BB, SCA, SHA, SCB, SHB)         \
  {                                                                    \
    float SA_ = SUM4(tA0) + SUM4(tA1) + SUM4(tA2) + SUM4(tA3) + SUM4(tA4); \
    float SB_ = SUM4(tB0) + SUM4(tB1) + SUM4(tB2) + SUM4(tB3) + SUM4(tB4); \
    if (qg == 1) { SA_ -= tA4[0]; SB_ -= tB4[0]; }                     \
    SA_ += __shfl_xor(SA_, 16, 64);                                    \
    SA_ += __shfl_xor(SA_, 32, 64);                                    \
    SB_ += __shfl_xor(SB_, 16, 64);                                    \
    SB_ += __shfl_xor(SB_, 32, 64);                                    \
    const u32 pk_ = (u32)__shfl((int)cvtpk(tA4[0], tB4[0]), 16 + p15, 64); \
    const float scA_ = (SCA), shA_ = (SHA), scB_ = (SCB), shB_ = (SHB);\
    const float cmtA_ = fmaf(CML, __uint_as_float(pk_ << 16), (BA));   \
    const float cmtB_ = fmaf(CML, __uint_as_float(pk_ & 0xffff0000u), (BB)); \
    float mvA_ = 0.f, mvB_ = 0.f;                                      \
    if (qg == 1) {                                                     \
      mvA_ = fmaf(fmaxf(fmaf(CML, SA_, fmaf(SELFM, tA4[0], (BA))), 0.f), scA_, shA_); \
      mvB_ = fmaf(fmaxf(fmaf(CML, SB_, fmaf(SELFM, tB4[0], (BB))), 0.f), scB_, shB_); \
      if (RESID) { mvA_ += hA4[0]; mvB_ += hB4[0]; }                   \
    }                                                                  \
    STEP2(0, tA0, tA4, tA1, tB0, tB4, tB1, hA0, hB0, RESID)            \
    STEP2(1, tA1, tA0, tA2, tB1, tB0, tB2, hA1, hB1, RESID)            \
    STEP2(2, tA2, tA1, tA3, tB2, tB1, tB3, hA2, hB2, RESID)            \
    STEP2(3, tA3, tA2, tA4, tB3, tB2, tB4, hA3, hB3, RESID)            \
    STEP2(4, tA4, tA3, tA0, tB4, tB3, tB0, hA4, hB4, RESID)            \
    if (qg == 1) { hA4[0] = mvA_; hB4[0] = mvB_; }                     \
    if (WRITE) {                                                       \
      u16* hw_ = (HBW);                                                \
      WPAIR2(hw_, 0, hA0, cqA) WPAIR2(hw_, 0, hB0, cqB)                \
      WPAIR2(hw_, 1, hA1, cqA) WPAIR2(hw_, 1, hB1, cqB)                \
      WPAIR2(hw_, 2, hA2, cqA) WPAIR2(hw_, 2, hB2, cqB)                \
      WPAIR2(hw_, 3, hA3, cqA) WPAIR2(hw_, 3, hB3, cqB)                \
      if (qg == 0) { WPAIR2(hw_, 4, hA4, cqA) WPAIR2(hw_, 4, hB4, cqB) } \
      else if (qg == 1) {                                              \
        hw_[68 * 64 + (cA ^ 32)] = (u16)cvtpk(mvA_, mvA_);             \
        hw_[68 * 64 + (cB ^ 32)] = (u16)cvtpk(mvB_, mvB_);             \
      }                                                                \
    }                                                                  \
  }

#define MM(A, B, C) __builtin_amdgcn_mfma_f32_16x16x32_bf16(A, B, C, 0, 0, 0)

// MFMA for one M-tile, BOTH N-tiles (A-fragments shared!)
#define MP3(HR, MT, TA, TB)                                            \
  {                                                                    \
    const short8 a0 = *(const short8*)&(HR)[(MT) * 1024 + ra0];        \
    const short8 a1 = *(const short8*)&(HR)[(MT) * 1024 + ra1];        \
    f32x4 accA = z4, accB = z4;                                        \
    accA = MM(a0, bA0, accA); accA = MM(a1, bA1, accA);                \
    accB = MM(a0, bB0, accB); accB = MM(a1, bB1, accB);                \
    TA = accA; TB = accB;                                              \
  }

__launch_bounds__(128)
__global__ void gcn_fused(
    const float* __restrict__ x,
    const float* __restrict__ cfW, const float* __restrict__ cfb,
    const float* __restrict__ cmb, const float* __restrict__ clb,
    const float* __restrict__ aW1, const float* __restrict__ ab1,
    const float* __restrict__ aW2, const float* __restrict__ ab2,
    const float* __restrict__ f1W, const float* __restrict__ f1b,
    const float* __restrict__ f2W, const float* __restrict__ f2b,
    const u16* __restrict__ frag, const float* __restrict__ bns,
    float* __restrict__ out) {
  // LDS: 20480 + 1280 + 256 + 768 + 512 = 23296 B -> 6 blocks/CU
  __shared__ u16 hb[2][80 * 64];  // bf16 h double-buffer, rows 69..79 stay 0
  __shared__ float xl4[80 * 4];   // staged x, rows 69..79 = 0
  __shared__ float mrow[64];      // final master h
  __shared__ float gv[192];       // readout concat [mean|max|master*att]
  __shared__ float part[128];     // cross-wave partials (att / fc1)

  const int tid = threadIdx.x;    // 0..127 (2 waves per graph)
  const int g = blockIdx.x;
  const int lane = tid & 63;
  const int w = tid >> 6;         // wave id: cols w*32..w*32+31
  const int p15 = lane & 15;
  const int qg = lane >> 4;
  const int cA = w * 32 + p15;    // first col
  const int cB = cA + 16;         // second col
  const f32x4 z4 = {0.f, 0.f, 0.f, 0.f};

  // A-frag read addresses (shared between both N-tiles)
  const int rsw = (p15 & 7) << 3;
  const int ra0 = (p15 * 64 + qg * 8) ^ rsw;
  const int ra1 = (p15 * 64 + 32 + qg * 8) ^ rsw;
  // write swizzle bases
  const int cqA = cA ^ ((qg & 1) << 5);
  const int cqB = cqA ^ 16;

  // prefetch layer-1 B fragments: nt = 2w (A-set), 2w+1 (B-set)
  const u16* f0p = frag + (((size_t)(2 * w) * 2) * 64 + lane) * 8;
  const u16* f1p = frag + (((size_t)(2 * w + 1) * 2) * 64 + lane) * 8;
  short8 bA0 = *(const short8*)f0p;
  short8 bA1 = *(const short8*)(f0p + 512);
  short8 bB0 = *(const short8*)f1p;
  short8 bB1 = *(const short8*)(f1p + 512);

  // zero ONLY pad rows 69..79 of both buffers (704 u32 total); stage x
  {
    u32* hz = (u32*)hb;
#pragma unroll
    for (int it = 0; it < 3; ++it) {
      const int i = tid + it * 128;
      if (i < 352) {
        hz[2208 + i] = 0u;          // buf0 pads
        hz[2560 + 2208 + i] = 0u;   // buf1 pads
      }
    }
  }
  if (tid < 69)
    *(f32x4*)&xl4[tid * 4] = *(const f32x4*)&x[((size_t)g * 69 + tid) * 4];
  else if (tid < 80)
    *(f32x4*)&xl4[tid * 4] = z4;

  f32x4 tA0, tA1, tA2, tA3, tA4, tB0, tB1, tB2, tB3, tB4;
  f32x4 hA0, hA1, hA2, hA3, hA4, hB0, hB1, hB2, hB3, hB4;

  __syncthreads();

  // ---- layer 0: t = x @ W_first (exact fp32, K=4), both col-sets
  {
    const float wA0 = cfW[cA], wA1 = cfW[64 + cA], wA2 = cfW[128 + cA], wA3 = cfW[192 + cA];
    const float wB0 = cfW[cB], wB1 = cfW[64 + cB], wB2 = cfW[128 + cB], wB3 = cfW[192 + cB];
#define L0T(MT, TA, TB)                                                \
    { _Pragma("unroll") for (int r = 0; r < 4; ++r) {                  \
        const f32x4 xv = *(const f32x4*)&xl4[(16 * (MT) + 4 * qg + r) * 4]; \
        TA[r] = fmaf(xv[0], wA0, fmaf(xv[1], wA1, fmaf(xv[2], wA2, xv[3] * wA3))); \
        TB[r] = fmaf(xv[0], wB0, fmaf(xv[1], wB1, fmaf(xv[2], wB2, xv[3] * wB3))); } }
    L0T(0, tA0, tB0) L0T(1, tA1, tB1) L0T(2, tA2, tB2) L0T(3, tA3, tB3) L0T(4, tA4, tB4)
#undef L0T
  }
  EPILOG2(false, true, &hb[0][0], cfb[cA], cfb[cB], bns[cA], bns[64 + cA],
          bns[cB], bns[64 + cB])
  __syncthreads();

  // ---- layers 1..6: MFMA + register epilogue (bn + residual)
#pragma unroll 1
  for (int l = 1; l <= 6; ++l) {
    // prefetch next layer's B-frags (stored layer index l = layer l+1)
    const u16* fA = frag + ((((size_t)l * 4 + 2 * w) * 2) * 64 + lane) * 8;
    const u16* fB = frag + ((((size_t)l * 4 + 2 * w + 1) * 2) * 64 + lane) * 8;
    const short8 nA0 = *(const short8*)fA;
    const short8 nA1 = *(const short8*)(fA + 512);
    const short8 nB0 = *(const short8*)fB;
    const short8 nB1 = *(const short8*)(fB + 512);
    const float biasA = cmb[(l - 1) * 64 + cA];
    const float biasB = cmb[(l - 1) * 64 + cB];
    const float lscA = bns[l * 128 + cA], lshA = bns[l * 128 + 64 + cA];
    const float lscB = bns[l * 128 + cB], lshB = bns[l * 128 + 64 + cB];
    const u16* hr = &hb[(l + 1) & 1][0];
    MP3(hr, 0, tA0, tB0) MP3(hr, 1, tA1, tB1) MP3(hr, 2, tA2, tB2)
    MP3(hr, 3, tA3, tB3) MP3(hr, 4, tA4, tB4)
    bA0 = nA0; bA1 = nA1; bB0 = nB0; bB1 = nB1;
    EPILOG2(true, true, &hb[l & 1][0], biasA, biasB, lscA, lshA, lscB, lshB)
    __syncthreads();
  }

  // ---- layer 7: MFMA + epilogue (no bn, no residual, no hb write)
  {
    const u16* hr = &hb[0][0];
    MP3(hr, 0, tA0, tB0) MP3(hr, 1, tA1, tB1) MP3(hr, 2, tA2, tB2)
    MP3(hr, 3, tA3, tB3) MP3(hr, 4, tA4, tB4)
    EPILOG2(false, false, (u16*)nullptr, clb[cA], clb[cB], 1.f, 0.f, 1.f, 0.f)
  }

  // ---- readout: per-col landmark mean/max from registers
  {
    float sA = SUM4(hA0) + SUM4(hA1) + SUM4(hA2) + SUM4(hA3);
    float sB = SUM4(hB0) + SUM4(hB1) + SUM4(hB2) + SUM4(hB3);
    float mA = fmaxf(fmaxf(MAX4(hA0), MAX4(hA1)), fmaxf(MAX4(hA2), MAX4(hA3)));
    float mB = fmaxf(fmaxf(MAX4(hB0), MAX4(hB1)), fmaxf(MAX4(hB2), MAX4(hB3)));
    if (qg == 0) {  // nodes 64..67 live in qg==0's mt=4 run
      sA += SUM4(hA4); mA = fmaxf(mA, MAX4(hA4));
      sB += SUM4(hB4); mB = fmaxf(mB, MAX4(hB4));
    }
    sA += __shfl_xor(sA, 16, 64); sA += __shfl_xor(sA, 32, 64);
    sB += __shfl_xor(sB, 16, 64); sB += __shfl_xor(sB, 32, 64);
    mA = fmaxf(mA, __shfl_xor(mA, 16, 64)); mA = fmaxf(mA, __shfl_xor(mA, 32, 64));
    mB = fmaxf(mB, __shfl_xor(mB, 16, 64)); mB = fmaxf(mB, __shfl_xor(mB, 32, 64));
    if (qg == 0) {
      gv[cA] = sA * (1.f / 68.f);
      gv[64 + cA] = mA;
      gv[cB] = sB * (1.f / 68.f);
      gv[64 + cB] = mB;
    }
    if (qg == 1) { mrow[cA] = hA4[0]; mrow[cB] = hB4[0]; }
  }
  __syncthreads();

  // ---- attention gate (k-split across the 2 waves)
  {
    const int f = tid & 63;
    const int kh = tid >> 6;
    float z = 0.f;
#pragma unroll
    for (int k = 0; k < 32; ++k)
      z = fmaf(mrow[kh * 32 + k], aW1[(kh * 32 + k) * 64 + f], z);
    part[tid] = z;
  }
  __syncthreads();
  if (tid < 64) {
    float z = part[tid] + part[64 + tid] + ab1[tid];
    z = fmaxf(z, 0.f);
    float pr = z * aW2[tid];
#pragma unroll
    for (int off = 32; off > 0; off >>= 1) pr += __shfl_xor(pr, off, 64);
    const float att = 1.f / (1.f + expf(-(pr + ab2[0])));
    gv[128 + tid] = mrow[tid] * att;
  }
  __syncthreads();

  // ---- fc1 partials (i-split across the 2 waves)
  {
    const int f = tid & 63;
    const int ih = tid >> 6;
    float a = 0.f;
#pragma unroll
    for (int i = 0; i < 96; ++i)
      a = fmaf(gv[ih * 96 + i], f1W[(ih * 96 + i) * 64 + f], a);
    part[tid] = a;
  }
  __syncthreads();
  if (tid < 64) {
    float a = part[tid] + part[64 + tid] + f1b[tid];
    const float y = fmaxf(a, 0.f);
    float po[7];
#pragma unroll
    for (int o = 0; o < 7; ++o) po[o] = y * f2W[tid * 7 + o];
#pragma unroll
    for (int o = 0; o < 7; ++o)
#pragma unroll
      for (int off = 32; off > 0; off >>= 1) po[o] += __shfl_xor(po[o], off, 64);
    if (tid == 0) {
#pragma unroll
      for (int o = 0; o < 7; ++o) out[(size_t)g * 7 + o] = po[o] + f2b[o];
    }
  }
}

extern "C" void kernel_launch(void* const* d_in, const int* in_sizes, int n_in,
                              void* d_out, int out_size, void* d_ws, size_t ws_size,
                              hipStream_t stream) {
  (void)in_sizes; (void)n_in; (void)ws_size;
  const float* x   = (const float*)d_in[0];
  const float* cfW = (const float*)d_in[4];
  const float* cfb = (const float*)d_in[5];
  const float* cmW = (const float*)d_in[6];
  const float* cmb = (const float*)d_in[7];
  const float* clW = (const float*)d_in[8];
  const float* clb = (const float*)d_in[9];
  const float* bng = (const float*)d_in[10];
  const float* bnb = (const float*)d_in[11];
  const float* bnm = (const float*)d_in[12];
  const float* bnv = (const float*)d_in[13];
  const float* aW1 = (const float*)d_in[14];
  const float* ab1 = (const float*)d_in[15];
  const float* aW2 = (const float*)d_in[16];
  const float* ab2 = (const float*)d_in[17];
  const float* f1W = (const float*)d_in[18];
  const float* f1b = (const float*)d_in[19];
  const float* f2W = (const float*)d_in[20];
  const float* f2b = (const float*)d_in[21];

  u16* frag = (u16*)d_ws;                      // 57344 B
  float* bns = (float*)((char*)d_ws + 57344);  // 7*128 floats
  const int ngraphs = out_size / 7;

  prep<<<dim3(16), dim3(256), 0, stream>>>(cmW, clW, bng, bnb, bnm, bnv, frag, bns);
  gcn_fused<<<dim3(ngraphs), dim3(128), 0, stream>>>(
      x, cfW, cfb, cmb, clb, aW1, ab1, aW2, ab2, f1W, f1b, f2W, f2b,
      frag, bns, (float*)d_out);
}